// Round 6
// baseline (117.476 us; speedup 1.0000x reference)
//
#include <hip/hip_runtime.h>
#include <math.h>

#define B 64
#define T 4096
#define D 512
#define NCH 32            // 128-row chunks per batch row
#define CHT (T / NCH)     // 128 t per chunk
#define WSTRIP 32         // t-rows per wave in K1

__device__ __forceinline__ float wave_sum64(float v) {
#pragma unroll
    for (int off = 32; off; off >>= 1)
        v += __shfl_xor(v, off, 64);
    return v;
}

// K1: attn_raw[b,t] = mask ? exp(key[b,t,:].query[b,:]/sqrt(D)) : 0 (exact),
// plus per-128-row chunk sums. grid = B*32, block = 256 (4 waves x 32 rows).
// Rows compacted per wave (ballot -> dense LDS list) so K loads are
// unconditional + dense; masked rows are never read, and butterfly/exp run
// only on live rows (~50%). Pad slots re-read list[0] (L1 hit) and force g=0.
__global__ __launch_bounds__(256) void energy_exp_kernel(const float* __restrict__ q,
                                                         const float* __restrict__ k,
                                                         const int* __restrict__ mask,
                                                         float* __restrict__ attn,
                                                         float* __restrict__ chunk_sums) {
    const float INV_SCALE = 0.04419417382415922f;  // 1/sqrt(512)

    __shared__ int sm_list[4][WSTRIP];
    __shared__ float sred[4];

    int blk = blockIdx.x;
    int b = blk >> 5;        // NCH = 32 chunks per b
    int ch = blk & 31;
    int wave = threadIdx.x >> 6;
    int lane = threadIdx.x & 63;

    const float* qb = q + b * D;
    float4 qa = *(const float4*)(qb + lane * 4);
    float4 qc = *(const float4*)(qb + 256 + lane * 4);

    int t0 = ch * CHT + wave * WSTRIP;
    const float* kbase = k + ((size_t)b * T + t0) * D;

    // 32-row mask bitmap + order-stable compaction into LDS (wave-local:
    // same-wave ds_write -> ds_read needs no barrier, lgkmcnt suffices)
    int mv = (lane < WSTRIP) ? mask[b * T + t0 + lane] : 0;
    unsigned int mbits = (unsigned int)__ballot(mv != 0);
    int cnt = __popc(mbits);
    if (lane < WSTRIP) {
        if (mv != 0) {
            int pre = __popc(mbits & ((1u << lane) - 1u));
            sm_list[wave][pre] = lane;
        } else {
            attn[(size_t)b * T + t0 + lane] = 0.0f;  // exact 0 for masked rows
        }
    }

    // slot owned by this lane after the 8-row butterfly: bits {5,4,3} -> {0,1,2}
    int r3 = ((lane >> 5) & 1) | (((lane >> 4) & 1) << 1) | (((lane >> 3) & 1) << 2);
    float gsum = 0.f;
    int ngrp = (cnt + 7) >> 3;

#pragma unroll 1
    for (int g = 0; g < ngrp; ++g) {
        float d8[8];
#pragma unroll
        for (int rr = 0; rr < 8; ++rr) {
            int slot = g * 8 + rr;
            int row = sm_list[wave][slot < cnt ? slot : 0];
            const float* kr = kbase + (size_t)row * D;
            float4 ka = *(const float4*)(kr + lane * 4);
            float4 kc = *(const float4*)(kr + 256 + lane * 4);
            d8[rr] = ka.x * qa.x + ka.y * qa.y + ka.z * qa.z + ka.w * qa.w
                   + kc.x * qc.x + kc.y * qc.y + kc.z * qc.z + kc.w * qc.w;
        }
        // multiplexed butterfly: 8 slots x 64 lanes -> full dots in 10 shuffles
        bool b5 = (lane & 32) != 0;
        float e[4];
#pragma unroll
        for (int i = 0; i < 4; ++i) {
            float u = b5 ? d8[2*i+1] : d8[2*i];
            float s = b5 ? d8[2*i]   : d8[2*i+1];
            e[i] = u + __shfl_xor(s, 32, 64);
        }
        bool b4 = (lane & 16) != 0;
        float f[2];
#pragma unroll
        for (int i = 0; i < 2; ++i) {
            float u = b4 ? e[2*i+1] : e[2*i];
            float s = b4 ? e[2*i]   : e[2*i+1];
            f[i] = u + __shfl_xor(s, 16, 64);
        }
        bool b3 = (lane & 8) != 0;
        float u = b3 ? f[1] : f[0];
        float s = b3 ? f[0] : f[1];
        float h = u + __shfl_xor(s, 8, 64);
        h += __shfl_xor(h, 4, 64);
        h += __shfl_xor(h, 2, 64);
        h += __shfl_xor(h, 1, 64);
        // h = dot for slot (g*8 + r3), replicated on 8 lanes

        int slot = g * 8 + r3;
        float gval = 0.f;
        if (slot < cnt) {
            gval = __expf(h * INV_SCALE);
            if ((lane & 7) == 0) {
                int row = sm_list[wave][slot];
                attn[(size_t)b * T + t0 + row] = gval;  // unnormalized
            }
        }
        gsum += gval;
    }

    // wave chunk-sum (each live row's g replicated on 8 lanes -> /8)
    float ws = wave_sum64(gsum) * 0.125f;
    if (lane == 0) sred[wave] = ws;
    __syncthreads();
    if (threadIdx.x == 0)
        chunk_sums[blk] = (sred[0] + sred[1]) + (sred[2] + sred[3]);
}

// K3: context partials + in-place attn normalization. grid = B*NCH, block 256.
// 2 t-streams (waves 0,1 / 2,3) x 128 lanes x float4 covers D=512.
// Stage attn chunk in LDS, wave-compact non-zero rows into a dense (row, a)
// list -> V gather loop is unconditional with SGPR bound -> deep pipelining.
// Denominator rebuilt per block from 32 chunk sums via identical fixed-order
// butterfly -> bitwise-deterministic and equal across blocks.
__global__ __launch_bounds__(256) void context_partial_kernel(float* __restrict__ attn,
                                                              const float* __restrict__ v,
                                                              const float* __restrict__ chunk_sums,
                                                              float* __restrict__ partial) {
    __shared__ float sa[CHT];
    __shared__ int   sm_c[4][64];
    __shared__ float sm_a[4][64];

    int blk = blockIdx.x;
    int b = blk >> 5;       // NCH = 32
    int ch = blk & 31;
    int tid = threadIdx.x;
    int wave = tid >> 6;
    int lane = tid & 63;

    float cs = (lane < NCH) ? chunk_sums[b * NCH + lane] : 0.f;
    float denom = wave_sum64(cs);
    float inv = 1.0f / denom;

    if (tid < CHT) sa[tid] = attn[(size_t)b * T + ch * CHT + tid];
    __syncthreads();

    int par = wave >> 1;               // t-stream: rows 2*i+par
    int dcol = ((wave & 1) * 64 + lane) * 4;

    // compact this stream's non-zero rows (lane i examines row 2*i+par)
    int myrow = 2 * lane + par;
    float mya0 = sa[myrow];
    unsigned long long ball = __ballot(mya0 != 0.0f);
    int cnt = __popcll(ball);
    int pre = __popcll(ball & ((1ull << lane) - 1ull));
    if (mya0 != 0.0f) {
        sm_c[wave][pre] = myrow;
        sm_a[wave][pre] = mya0;
    }
    __syncthreads();

    int  crow = sm_c[wave][lane];      // compacted row index held per lane
    float ca  = sm_a[wave][lane];

    const float* vb = v + ((size_t)b * T + ch * CHT) * D + dcol;

    float4 acc = {0.f, 0.f, 0.f, 0.f};
#pragma unroll 8
    for (int j = 0; j < cnt; ++j) {
        int row = __shfl(crow, j, 64);
        float a = __shfl(ca, j, 64);
        float4 vv = *(const float4*)(vb + (size_t)row * D);
        acc.x += a * vv.x; acc.y += a * vv.y;
        acc.z += a * vv.z; acc.w += a * vv.w;
    }
    acc.x *= inv; acc.y *= inv; acc.z *= inv; acc.w *= inv;
    *(float4*)(partial + ((size_t)(b * 64 + ch * 2 + par)) * D + dcol) = acc;

    // in-place attn normalization from the staged copy
    if (tid < CHT)
        attn[(size_t)b * T + ch * CHT + tid] = sa[tid] * inv;
}

// K4: reduce 64 partial rows -> context. grid = B, block = 256.
__global__ __launch_bounds__(256) void context_reduce_kernel(const float* __restrict__ partial,
                                                             float* __restrict__ ctx) {
    int b = blockIdx.x;
    int tid = threadIdx.x;
    int d0 = tid * 2;
    float2 acc = {0.f, 0.f};
#pragma unroll 8
    for (int j = 0; j < 64; ++j) {
        float2 p = *(const float2*)(partial + ((size_t)(b * 64 + j)) * D + d0);
        acc.x += p.x;
        acc.y += p.y;
    }
    *(float2*)(ctx + (size_t)b * D + d0) = acc;
}

extern "C" void kernel_launch(void* const* d_in, const int* in_sizes, int n_in,
                              void* d_out, int out_size, void* d_ws, size_t ws_size,
                              hipStream_t stream) {
    const float* q    = (const float*)d_in[0];
    const float* k    = (const float*)d_in[1];
    const float* v    = (const float*)d_in[2];
    const int*   mask = (const int*)d_in[3];

    float* ctx  = (float*)d_out;            // [B, D]
    float* attn = (float*)d_out + B * D;    // [B, T]

    float* chunk_sums = (float*)d_ws;            // B*NCH floats = 8 KB
    float* partial    = (float*)d_ws + 8192;     // [B*64, D] = 8.4 MB

    energy_exp_kernel<<<B * NCH, 256, 0, stream>>>(q, k, mask, attn, chunk_sums);
    context_partial_kernel<<<B * NCH, 256, 0, stream>>>(attn, v, chunk_sums, partial);
    context_reduce_kernel<<<B, 256, 0, stream>>>(partial, ctx);
}

// Round 7
// 112.912 us; speedup vs baseline: 1.0404x; 1.0404x over previous
//
#include <hip/hip_runtime.h>
#include <math.h>

#define B 64
#define T 4096
#define D 512
#define NCH 32            // 128-row chunks per batch row
#define CHT (T / NCH)     // 128 t per chunk
#define WSTRIP 32         // t-rows per wave in K1
#define VBATCH 8          // V rows per pipeline batch in K3

typedef __attribute__((address_space(1))) const void global_cv;
typedef __attribute__((address_space(3))) void lds_v;

__device__ __forceinline__ float wave_sum64(float v) {
#pragma unroll
    for (int off = 32; off; off >>= 1)
        v += __shfl_xor(v, off, 64);
    return v;
}

// Async-stage one 2KB V row into LDS: 2 x (64 lanes x 16B) global_load_lds.
// LDS dest is the wave-uniform row base (HW adds lane*16); global src is
// per-lane. Increments vmcnt by 2 per call site per wave.
__device__ __forceinline__ void stage_row(const float* __restrict__ gsrc_row,
                                          float* lds_row, int lane) {
    __builtin_amdgcn_global_load_lds((global_cv*)(gsrc_row + lane * 4),
                                     (lds_v*)(lds_row), 16, 0, 0);
    __builtin_amdgcn_global_load_lds((global_cv*)(gsrc_row + 256 + lane * 4),
                                     (lds_v*)(lds_row + 256), 16, 0, 0);
}

// K1 (unchanged from R6): attn_raw[b,t] = mask ? exp(k.q/sqrt(D)) : 0 exact,
// per-128-row chunk sums. grid = B*32, block = 256 (4 waves x 32 rows).
__global__ __launch_bounds__(256) void energy_exp_kernel(const float* __restrict__ q,
                                                         const float* __restrict__ k,
                                                         const int* __restrict__ mask,
                                                         float* __restrict__ attn,
                                                         float* __restrict__ chunk_sums) {
    const float INV_SCALE = 0.04419417382415922f;  // 1/sqrt(512)

    __shared__ int sm_list[4][WSTRIP];
    __shared__ float sred[4];

    int blk = blockIdx.x;
    int b = blk >> 5;
    int ch = blk & 31;
    int wave = threadIdx.x >> 6;
    int lane = threadIdx.x & 63;

    const float* qb = q + b * D;
    float4 qa = *(const float4*)(qb + lane * 4);
    float4 qc = *(const float4*)(qb + 256 + lane * 4);

    int t0 = ch * CHT + wave * WSTRIP;
    const float* kbase = k + ((size_t)b * T + t0) * D;

    int mv = (lane < WSTRIP) ? mask[b * T + t0 + lane] : 0;
    unsigned int mbits = (unsigned int)__ballot(mv != 0);
    int cnt = __popc(mbits);
    if (lane < WSTRIP) {
        if (mv != 0) {
            int pre = __popc(mbits & ((1u << lane) - 1u));
            sm_list[wave][pre] = lane;
        } else {
            attn[(size_t)b * T + t0 + lane] = 0.0f;
        }
    }

    int r3 = ((lane >> 5) & 1) | (((lane >> 4) & 1) << 1) | (((lane >> 3) & 1) << 2);
    float gsum = 0.f;
    int ngrp = (cnt + 7) >> 3;

#pragma unroll 1
    for (int g = 0; g < ngrp; ++g) {
        float d8[8];
#pragma unroll
        for (int rr = 0; rr < 8; ++rr) {
            int slot = g * 8 + rr;
            int row = sm_list[wave][slot < cnt ? slot : 0];
            const float* kr = kbase + (size_t)row * D;
            float4 ka = *(const float4*)(kr + lane * 4);
            float4 kc = *(const float4*)(kr + 256 + lane * 4);
            d8[rr] = ka.x * qa.x + ka.y * qa.y + ka.z * qa.z + ka.w * qa.w
                   + kc.x * qc.x + kc.y * qc.y + kc.z * qc.z + kc.w * qc.w;
        }
        bool b5 = (lane & 32) != 0;
        float e[4];
#pragma unroll
        for (int i = 0; i < 4; ++i) {
            float u = b5 ? d8[2*i+1] : d8[2*i];
            float s = b5 ? d8[2*i]   : d8[2*i+1];
            e[i] = u + __shfl_xor(s, 32, 64);
        }
        bool b4 = (lane & 16) != 0;
        float f[2];
#pragma unroll
        for (int i = 0; i < 2; ++i) {
            float u = b4 ? e[2*i+1] : e[2*i];
            float s = b4 ? e[2*i]   : e[2*i+1];
            f[i] = u + __shfl_xor(s, 16, 64);
        }
        bool b3 = (lane & 8) != 0;
        float u = b3 ? f[1] : f[0];
        float s = b3 ? f[0] : f[1];
        float h = u + __shfl_xor(s, 8, 64);
        h += __shfl_xor(h, 4, 64);
        h += __shfl_xor(h, 2, 64);
        h += __shfl_xor(h, 1, 64);

        int slot = g * 8 + r3;
        float gval = 0.f;
        if (slot < cnt) {
            gval = __expf(h * INV_SCALE);
            if ((lane & 7) == 0) {
                int row = sm_list[wave][slot];
                attn[(size_t)b * T + t0 + row] = gval;
            }
        }
        gsum += gval;
    }

    float ws = wave_sum64(gsum) * 0.125f;
    if (lane == 0) sred[wave] = ws;
    __syncthreads();
    if (threadIdx.x == 0)
        chunk_sums[blk] = (sred[0] + sred[1]) + (sred[2] + sred[3]);
}

// K3 (REBUILT): DMA-pipelined V accumulation. grid = B*NCH, block = 256.
// Live rows compacted (order-stable); V rows streamed through a 2x8-row
// LDS double buffer via global_load_lds with counted vmcnt(4) + raw
// s_barrier (no __syncthreads in the loop -> queue never drains).
// Each thread owns a float2 column pair; accumulation in list (=t) order.
// One partial row per block. Denominator rebuilt via fixed-order butterfly.
__global__ __launch_bounds__(256) void context_partial_kernel(float* __restrict__ attn,
                                                              const float* __restrict__ v,
                                                              const float* __restrict__ chunk_sums,
                                                              float* __restrict__ partial) {
    __shared__ __align__(16) float vbuf[2][VBATCH][D];   // 32 KB
    __shared__ float sa_raw[CHT];
    __shared__ int   rows[CHT + VBATCH];
    __shared__ float avals[CHT + VBATCH];
    __shared__ int   scnt;

    int blk = blockIdx.x;
    int b = blk >> 5;
    int ch = blk & 31;
    int tid = threadIdx.x;
    int wave = tid >> 6;
    int lane = tid & 63;

    float cs = (lane < NCH) ? chunk_sums[b * NCH + lane] : 0.f;
    float denom = wave_sum64(cs);
    float inv = 1.0f / denom;

    if (tid < CHT) sa_raw[tid] = attn[(size_t)b * T + ch * CHT + tid];
    __syncthreads();

    if (wave == 0) {
        // order-stable compaction of 128 rows (two 64-row passes, wave 0)
        float a0 = sa_raw[lane];
        unsigned long long bl0 = __ballot(a0 != 0.0f);
        int c0 = __popcll(bl0);
        if (a0 != 0.0f) {
            int p = __popcll(bl0 & ((1ull << lane) - 1ull));
            rows[p] = lane; avals[p] = a0;
        }
        float a1 = sa_raw[64 + lane];
        unsigned long long bl1 = __ballot(a1 != 0.0f);
        int c1 = __popcll(bl1);
        if (a1 != 0.0f) {
            int p = c0 + __popcll(bl1 & ((1ull << lane) - 1ull));
            rows[p] = 64 + lane; avals[p] = a1;
        }
        int cnt = c0 + c1;
        if (lane < VBATCH) {           // pad slots: re-stage row[0] (L2 hit), a=0
            int safe0 = (cnt > 0) ? rows[0] : 0;
            rows[cnt + lane] = safe0;
            avals[cnt + lane] = 0.0f;
        }
        if (lane == 0) scnt = cnt;
    }
    __syncthreads();

    int cnt = scnt;
    int nb = (cnt + VBATCH - 1) / VBATCH;
    const float* vchunk = v + ((size_t)b * T + ch * CHT) * D;

    // prologue: stage batches 0 and 1 (each wave stages its 2 rows = 4 vmcnt)
    if (nb > 0) {
        int s0 = wave * 2;
        stage_row(vchunk + (size_t)rows[s0] * D,     &vbuf[0][wave * 2][0],     lane);
        stage_row(vchunk + (size_t)rows[s0 + 1] * D, &vbuf[0][wave * 2 + 1][0], lane);
    }
    if (nb > 1) {
        int s0 = VBATCH + wave * 2;
        stage_row(vchunk + (size_t)rows[s0] * D,     &vbuf[1][wave * 2][0],     lane);
        stage_row(vchunk + (size_t)rows[s0 + 1] * D, &vbuf[1][wave * 2 + 1][0], lane);
    }

    float2 acc = {0.f, 0.f};
    int c0 = tid * 2;
#pragma unroll 1
    for (int i = 0; i < nb; ++i) {
        // wait for batch i (own 4 loads beyond the in-flight next batch)
        if (i + 1 < nb) asm volatile("s_waitcnt vmcnt(4)" ::: "memory");
        else            asm volatile("s_waitcnt vmcnt(0)" ::: "memory");
        __builtin_amdgcn_s_barrier();   // all waves' batch-i stages landed

        const float (*buf)[D] = vbuf[i & 1];
        int base = i * VBATCH;
#pragma unroll
        for (int r = 0; r < VBATCH; ++r) {
            float a = avals[base + r];                    // LDS broadcast
            float2 vv = *(const float2*)&buf[r][c0];      // ds_read_b64
            acc.x += a * vv.x;
            acc.y += a * vv.y;
        }
        __builtin_amdgcn_s_barrier();   // all reads of buf done before overwrite

        if (i + 2 < nb) {
            int s0 = (i + 2) * VBATCH + wave * 2;
            stage_row(vchunk + (size_t)rows[s0] * D,     &vbuf[i & 1][wave * 2][0],     lane);
            stage_row(vchunk + (size_t)rows[s0 + 1] * D, &vbuf[i & 1][wave * 2 + 1][0], lane);
        }
    }

    acc.x *= inv; acc.y *= inv;
    *(float2*)(partial + (size_t)(b * NCH + ch) * D + c0) = acc;

    if (tid < CHT)
        attn[(size_t)b * T + ch * CHT + tid] = sa_raw[tid] * inv;
}

// K4: reduce 32 partial rows -> context. grid = B, block = 256.
__global__ __launch_bounds__(256) void context_reduce_kernel(const float* __restrict__ partial,
                                                             float* __restrict__ ctx) {
    int b = blockIdx.x;
    int tid = threadIdx.x;
    int d0 = tid * 2;
    float2 acc = {0.f, 0.f};
#pragma unroll 8
    for (int j = 0; j < NCH; ++j) {
        float2 p = *(const float2*)(partial + (size_t)(b * NCH + j) * D + d0);
        acc.x += p.x;
        acc.y += p.y;
    }
    *(float2*)(ctx + (size_t)b * D + d0) = acc;
}

extern "C" void kernel_launch(void* const* d_in, const int* in_sizes, int n_in,
                              void* d_out, int out_size, void* d_ws, size_t ws_size,
                              hipStream_t stream) {
    const float* q    = (const float*)d_in[0];
    const float* k    = (const float*)d_in[1];
    const float* v    = (const float*)d_in[2];
    const int*   mask = (const int*)d_in[3];

    float* ctx  = (float*)d_out;            // [B, D]
    float* attn = (float*)d_out + B * D;    // [B, T]

    float* chunk_sums = (float*)d_ws;            // B*NCH floats = 8 KB
    float* partial    = (float*)d_ws + 8192;     // [B*NCH, D] = 4.2 MB

    energy_exp_kernel<<<B * NCH, 256, 0, stream>>>(q, k, mask, attn, chunk_sums);
    context_partial_kernel<<<B * NCH, 256, 0, stream>>>(attn, v, chunk_sums, partial);
    context_reduce_kernel<<<B, 256, 0, stream>>>(partial, ctx);
}

// Round 8
// 111.351 us; speedup vs baseline: 1.0550x; 1.0140x over previous
//
#include <hip/hip_runtime.h>
#include <math.h>

#define B 64
#define T 4096
#define D 512
#define NCH 32            // 128-row chunks per batch row
#define CHT (T / NCH)     // 128 t per chunk
#define WSTRIP 32         // t-rows per wave in K1
#define KBATCH 4          // K rows per pipeline batch per wave in K1
#define VBATCH 8          // V rows per pipeline batch in K3

typedef __attribute__((address_space(1))) const void global_cv;
typedef __attribute__((address_space(3))) void lds_v;

__device__ __forceinline__ float wave_sum64(float v) {
#pragma unroll
    for (int off = 32; off; off >>= 1)
        v += __shfl_xor(v, off, 64);
    return v;
}

// Async-stage one 2KB row into LDS: 2 x (64 lanes x 16B) global_load_lds.
// LDS dest is the wave-uniform row base (HW adds lane*16); global src is
// per-lane. Increments vmcnt by 2 per call per wave.
__device__ __forceinline__ void stage_row(const float* __restrict__ gsrc_row,
                                          float* lds_row, int lane) {
    __builtin_amdgcn_global_load_lds((global_cv*)(gsrc_row + lane * 4),
                                     (lds_v*)(lds_row), 16, 0, 0);
    __builtin_amdgcn_global_load_lds((global_cv*)(gsrc_row + 256 + lane * 4),
                                     (lds_v*)(lds_row + 256), 16, 0, 0);
}

// K1 (REBUILT): DMA-pipelined energy+exp. grid = B*32, block = 256
// (4 waves x 32-row strip). Live rows compacted per wave; K rows stream
// through a per-wave 2x4-row LDS double buffer (global_load_lds, counted
// vmcnt(8), NO barriers -- waves fully independent). 4-row multiplexed
// butterfly from LDS; masked rows never read; pad slots re-stage the first
// live row (L2 hit) with g forced to 0.
__global__ __launch_bounds__(256) void energy_exp_kernel(const float* __restrict__ q,
                                                         const float* __restrict__ k,
                                                         const int* __restrict__ mask,
                                                         float* __restrict__ attn,
                                                         float* __restrict__ chunk_sums) {
    const float INV_SCALE = 0.04419417382415922f;  // 1/sqrt(512)

    __shared__ __align__(16) float kbuf[2][4][KBATCH][D];   // 64 KB
    __shared__ int sm_list[4][WSTRIP + KBATCH];
    __shared__ float sred[4];

    int blk = blockIdx.x;
    int b = blk >> 5;
    int ch = blk & 31;
    int wave = threadIdx.x >> 6;
    int lane = threadIdx.x & 63;

    const float* qb = q + b * D;
    float4 qa = *(const float4*)(qb + lane * 4);
    float4 qc = *(const float4*)(qb + 256 + lane * 4);

    int t0 = ch * CHT + wave * WSTRIP;
    const float* kbase = k + ((size_t)b * T + t0) * D;

    // 32-row mask bitmap + order-stable compaction (wave-local LDS list)
    int mv = (lane < WSTRIP) ? mask[b * T + t0 + lane] : 0;
    unsigned int mbits = (unsigned int)__ballot(mv != 0);
    int cnt = __popc(mbits);
    int row0 = (cnt > 0) ? (__ffs(mbits) - 1) : 0;   // uniform, no LDS read
    if (lane < WSTRIP) {
        if (mv != 0) {
            int pre = __popc(mbits & ((1u << lane) - 1u));
            sm_list[wave][pre] = lane;
        } else {
            attn[(size_t)b * T + t0 + lane] = 0.0f;  // exact 0 for masked rows
        }
    }
    if (lane < KBATCH) sm_list[wave][cnt + lane] = row0;  // pad slots

    int ngrp = (cnt + KBATCH - 1) >> 2;

    // prologue: stage batches 0 and 1 (4 rows = 8 vmcnt each, per wave)
    if (ngrp > 0) {
#pragma unroll
        for (int r = 0; r < KBATCH; ++r)
            stage_row(kbase + (size_t)sm_list[wave][r] * D, &kbuf[0][wave][r][0], lane);
    }
    if (ngrp > 1) {
#pragma unroll
        for (int r = 0; r < KBATCH; ++r)
            stage_row(kbase + (size_t)sm_list[wave][KBATCH + r] * D, &kbuf[1][wave][r][0], lane);
    }

    // slot owned by this lane after the 4-row butterfly: bits {5,4} -> {0,1}
    int r2 = ((lane >> 5) & 1) | (((lane >> 4) & 1) << 1);
    float gsum = 0.f;

#pragma unroll 1
    for (int i = 0; i < ngrp; ++i) {
        if (i + 1 < ngrp) asm volatile("s_waitcnt vmcnt(8)" ::: "memory");
        else              asm volatile("s_waitcnt vmcnt(0)" ::: "memory");

        const float (*buf)[D] = kbuf[i & 1][wave];
        float d4[KBATCH];
#pragma unroll
        for (int rr = 0; rr < KBATCH; ++rr) {
            float4 ka = *(const float4*)&buf[rr][lane * 4];
            float4 kc = *(const float4*)&buf[rr][256 + lane * 4];
            d4[rr] = ka.x * qa.x + ka.y * qa.y + ka.z * qa.z + ka.w * qa.w
                   + kc.x * qc.x + kc.y * qc.y + kc.z * qc.z + kc.w * qc.w;
        }
        // ds_reads of this buffer complete before re-staging over it
        asm volatile("s_waitcnt lgkmcnt(0)" ::: "memory");
        if (i + 2 < ngrp) {
            int s0 = (i + 2) * KBATCH;
#pragma unroll
            for (int r = 0; r < KBATCH; ++r)
                stage_row(kbase + (size_t)sm_list[wave][s0 + r] * D,
                          &kbuf[i & 1][wave][r][0], lane);
        }

        // multiplexed butterfly: 4 slots x 64 lanes -> full dots in 7 shuffles
        bool b5 = (lane & 32) != 0;
        float e[2];
#pragma unroll
        for (int j = 0; j < 2; ++j) {
            float u = b5 ? d4[2*j+1] : d4[2*j];
            float s = b5 ? d4[2*j]   : d4[2*j+1];
            e[j] = u + __shfl_xor(s, 32, 64);
        }
        bool b4 = (lane & 16) != 0;
        float u = b4 ? e[1] : e[0];
        float s = b4 ? e[0] : e[1];
        float h = u + __shfl_xor(s, 16, 64);
        h += __shfl_xor(h, 8, 64);
        h += __shfl_xor(h, 4, 64);
        h += __shfl_xor(h, 2, 64);
        h += __shfl_xor(h, 1, 64);
        // h = dot for slot (i*4 + r2), replicated on 16 lanes (bits 3..0 free)

        int slot = i * KBATCH + r2;
        float gval = 0.f;
        if (slot < cnt) {
            gval = __expf(h * INV_SCALE);
            if ((lane & 15) == 0) {
                int row = sm_list[wave][slot];
                attn[(size_t)b * T + t0 + row] = gval;  // unnormalized
            }
        }
        gsum += gval;
    }

    // wave chunk-sum (each live row's g replicated on 16 lanes -> /16)
    float ws = wave_sum64(gsum) * 0.0625f;
    if (lane == 0) sred[wave] = ws;
    __syncthreads();
    if (threadIdx.x == 0)
        chunk_sums[blk] = (sred[0] + sred[1]) + (sred[2] + sred[3]);
}

// K3 (unchanged from R7): DMA-pipelined V accumulation. grid = B*NCH.
__global__ __launch_bounds__(256) void context_partial_kernel(float* __restrict__ attn,
                                                              const float* __restrict__ v,
                                                              const float* __restrict__ chunk_sums,
                                                              float* __restrict__ partial) {
    __shared__ __align__(16) float vbuf[2][VBATCH][D];   // 32 KB
    __shared__ float sa_raw[CHT];
    __shared__ int   rows[CHT + VBATCH];
    __shared__ float avals[CHT + VBATCH];
    __shared__ int   scnt;

    int blk = blockIdx.x;
    int b = blk >> 5;
    int ch = blk & 31;
    int tid = threadIdx.x;
    int wave = tid >> 6;
    int lane = tid & 63;

    float cs = (lane < NCH) ? chunk_sums[b * NCH + lane] : 0.f;
    float denom = wave_sum64(cs);
    float inv = 1.0f / denom;

    if (tid < CHT) sa_raw[tid] = attn[(size_t)b * T + ch * CHT + tid];
    __syncthreads();

    if (wave == 0) {
        float a0 = sa_raw[lane];
        unsigned long long bl0 = __ballot(a0 != 0.0f);
        int c0 = __popcll(bl0);
        if (a0 != 0.0f) {
            int p = __popcll(bl0 & ((1ull << lane) - 1ull));
            rows[p] = lane; avals[p] = a0;
        }
        float a1 = sa_raw[64 + lane];
        unsigned long long bl1 = __ballot(a1 != 0.0f);
        int c1 = __popcll(bl1);
        if (a1 != 0.0f) {
            int p = c0 + __popcll(bl1 & ((1ull << lane) - 1ull));
            rows[p] = 64 + lane; avals[p] = a1;
        }
        int cnt = c0 + c1;
        if (lane < VBATCH) {
            int safe0 = (cnt > 0) ? rows[0] : 0;
            rows[cnt + lane] = safe0;
            avals[cnt + lane] = 0.0f;
        }
        if (lane == 0) scnt = cnt;
    }
    __syncthreads();

    int cnt = scnt;
    int nb = (cnt + VBATCH - 1) / VBATCH;
    const float* vchunk = v + ((size_t)b * T + ch * CHT) * D;

    if (nb > 0) {
        int s0 = wave * 2;
        stage_row(vchunk + (size_t)rows[s0] * D,     &vbuf[0][wave * 2][0],     lane);
        stage_row(vchunk + (size_t)rows[s0 + 1] * D, &vbuf[0][wave * 2 + 1][0], lane);
    }
    if (nb > 1) {
        int s0 = VBATCH + wave * 2;
        stage_row(vchunk + (size_t)rows[s0] * D,     &vbuf[1][wave * 2][0],     lane);
        stage_row(vchunk + (size_t)rows[s0 + 1] * D, &vbuf[1][wave * 2 + 1][0], lane);
    }

    float2 acc = {0.f, 0.f};
    int c0 = tid * 2;
#pragma unroll 1
    for (int i = 0; i < nb; ++i) {
        if (i + 1 < nb) asm volatile("s_waitcnt vmcnt(4)" ::: "memory");
        else            asm volatile("s_waitcnt vmcnt(0)" ::: "memory");
        __builtin_amdgcn_s_barrier();

        const float (*buf)[D] = vbuf[i & 1];
        int base = i * VBATCH;
#pragma unroll
        for (int r = 0; r < VBATCH; ++r) {
            float a = avals[base + r];
            float2 vv = *(const float2*)&buf[r][c0];
            acc.x += a * vv.x;
            acc.y += a * vv.y;
        }
        __builtin_amdgcn_s_barrier();

        if (i + 2 < nb) {
            int s0 = (i + 2) * VBATCH + wave * 2;
            stage_row(vchunk + (size_t)rows[s0] * D,     &vbuf[i & 1][wave * 2][0],     lane);
            stage_row(vchunk + (size_t)rows[s0 + 1] * D, &vbuf[i & 1][wave * 2 + 1][0], lane);
        }
    }

    acc.x *= inv; acc.y *= inv;
    *(float2*)(partial + (size_t)(b * NCH + ch) * D + c0) = acc;

    if (tid < CHT)
        attn[(size_t)b * T + ch * CHT + tid] = sa_raw[tid] * inv;
}

// K4: reduce 32 partial rows -> context. grid = B, block = 256.
__global__ __launch_bounds__(256) void context_reduce_kernel(const float* __restrict__ partial,
                                                             float* __restrict__ ctx) {
    int b = blockIdx.x;
    int tid = threadIdx.x;
    int d0 = tid * 2;
    float2 acc = {0.f, 0.f};
#pragma unroll 8
    for (int j = 0; j < NCH; ++j) {
        float2 p = *(const float2*)(partial + (size_t)(b * NCH + j) * D + d0);
        acc.x += p.x;
        acc.y += p.y;
    }
    *(float2*)(ctx + (size_t)b * D + d0) = acc;
}

extern "C" void kernel_launch(void* const* d_in, const int* in_sizes, int n_in,
                              void* d_out, int out_size, void* d_ws, size_t ws_size,
                              hipStream_t stream) {
    const float* q    = (const float*)d_in[0];
    const float* k    = (const float*)d_in[1];
    const float* v    = (const float*)d_in[2];
    const int*   mask = (const int*)d_in[3];

    float* ctx  = (float*)d_out;            // [B, D]
    float* attn = (float*)d_out + B * D;    // [B, T]

    float* chunk_sums = (float*)d_ws;            // B*NCH floats = 8 KB
    float* partial    = (float*)d_ws + 8192;     // [B*NCH, D] = 4.2 MB

    energy_exp_kernel<<<B * NCH, 256, 0, stream>>>(q, k, mask, attn, chunk_sums);
    context_partial_kernel<<<B * NCH, 256, 0, stream>>>(attn, v, chunk_sums, partial);
    context_reduce_kernel<<<B, 256, 0, stream>>>(partial, ctx);
}